// Round 9
// baseline (260.878 us; speedup 1.0000x reference)
//
#include <hip/hip_runtime.h>

typedef float f4 __attribute__((ext_vector_type(4)));

#define BB   16
#define NN   512
#define DIN  256
#define COUT 32
#define CCS  48
#define HH   256
#define WWG  256
#define HW   (HH * WWG)          // 65536 = 1<<16
#define CTOT (CCS + COUT)        // 80

// ---------------------------------------------------------------------------
// R2-proven: blocks [0,1024): proj = emb·W + b (8 entity-rows/block, W in LDS);
// blocks [1024,1056): winner atomicMax (one entity/thread, 32 parallel blocks).
// winner[] pre-set to -1 by async memset (0xFF).
// ---------------------------------------------------------------------------
__global__ __launch_bounds__(256) void k_projwin(
        const float* __restrict__ emb, const float* __restrict__ Wm,
        const float* __restrict__ bias, const int* __restrict__ loc,
        float* __restrict__ proj, int* __restrict__ winner) {
    __shared__ float Wl[DIN * COUT];
    int tid = threadIdx.x;
    if (blockIdx.x < 1024) {
        for (int i = tid; i < DIN * COUT; i += 256) Wl[i] = Wm[i];
        __syncthreads();
        int c = tid & 31;
        int r = tid >> 5;                        // 0..7
        int row = blockIdx.x * 8 + r;            // flat entity index, 0..8191
        const float* e = emb + (size_t)row * DIN;
        float acc = bias[c];
        #pragma unroll 8
        for (int d = 0; d < DIN; ++d)
            acc += e[d] * Wl[d * COUT + c];      // e[d] uniform broadcast; conflict-free
        proj[(size_t)row * COUT + c] = acc;
    } else {
        int i = (blockIdx.x - 1024) * 256 + tid; // flat entity index
        int b = i >> 9;
        int h = loc[2 * i + 0];
        int w = loc[2 * i + 1];
        atomicMax(&winner[b * HW + h * WWG + w], i);  // max flat == last-write-wins
    }
}

// ---------------------------------------------------------------------------
// Pure spatial copy (branch-free): out[b, ch, :] = sp[b, ch, :], ch in [0,48).
// Proven pattern: 1 float4/thread, grid (64, 48, 16), nontemporal.
// Zero channels are handled by a separate hipMemset2DAsync node.
// ---------------------------------------------------------------------------
__global__ __launch_bounds__(256) void k_copy(const float* __restrict__ sp,
                                              float* __restrict__ out) {
    int pix4 = blockIdx.x * 256 + threadIdx.x;   // f4 index within channel image
    int ch = blockIdx.y;                         // 0..47
    int b  = blockIdx.z;
    const f4* s = (const f4*)sp + (((size_t)(b * CCS + ch) << 14) + pix4);
    f4 v = __builtin_nontemporal_load(s);
    f4* o = (f4*)out + (((size_t)(b * CTOT + ch) << 14) + pix4);
    __builtin_nontemporal_store(v, o);
}

// ---------------------------------------------------------------------------
// Winning entity writes its 32-channel proj vector to out[b, 48+c, h, w].
// ---------------------------------------------------------------------------
__global__ __launch_bounds__(256) void k_scatter(
        const float* __restrict__ proj, const int* __restrict__ loc,
        const int* __restrict__ winner, float* __restrict__ out) {
    int t = blockIdx.x * 256 + threadIdx.x;
    int c = t & 31;
    int i = t >> 5;                              // flat entity index
    int b = i >> 9;
    int h = loc[2 * i + 0];
    int w = loc[2 * i + 1];
    int cell = b * HW + h * WWG + w;
    if (winner[cell] != i) return;               // last-write-wins (max flat index)
    out[((size_t)(b * CTOT + CCS + c) << 16) + (size_t)h * WWG + w] =
        proj[(size_t)i * COUT + c];
}

extern "C" void kernel_launch(void* const* d_in, const int* in_sizes, int n_in,
                              void* d_out, int out_size, void* d_ws, size_t ws_size,
                              hipStream_t stream) {
    const float* sp   = (const float*)d_in[0];   // [16,48,256,256]
    const float* emb  = (const float*)d_in[1];   // [16,512,256]
    const float* Wm   = (const float*)d_in[2];   // [256,32]
    const float* bias = (const float*)d_in[3];   // [32]
    const int*   loc  = (const int*)d_in[4];     // [16,512,2]
    float* out = (float*)d_out;                  // [16,80,256,256]

    float* proj   = (float*)d_ws;                                     // 1 MB
    int*   winner = (int*)((char*)d_ws + (size_t)BB * NN * COUT * 4); // 4 MB

    // winner = -1 everywhere
    hipMemsetAsync(winner, 0xFF, (size_t)BB * HW * sizeof(int), stream);

    // Zero the 32 scatter channels: out[b, 48:80, :, :] is one contiguous
    // 8.39 MB row per batch at uniform 20.97 MB pitch -> single 2D memset.
    hipMemset2DAsync(out + ((size_t)CCS << 16),               // first zero row
                     (size_t)CTOT * HW * sizeof(float),       // pitch (bytes)
                     0,
                     (size_t)COUT * HW * sizeof(float),       // width (bytes)
                     BB, stream);

    hipLaunchKernelGGL(k_projwin, dim3(1024 + BB * NN / 256), dim3(256), 0, stream,
                       emb, Wm, bias, loc, proj, winner);

    hipLaunchKernelGGL(k_copy, dim3(HW / 4 / 256, CCS, BB), dim3(256), 0, stream,
                       sp, out);

    hipLaunchKernelGGL(k_scatter, dim3(BB * NN * COUT / 256), dim3(256), 0, stream,
                       proj, loc, winner, out);
}

// Round 10
// 129.861 us; speedup vs baseline: 2.0089x; 2.0089x over previous
//
#include <hip/hip_runtime.h>

typedef float f4 __attribute__((ext_vector_type(4)));

#define BB   16
#define NN   512
#define DIN  256
#define COUT 32
#define CCS  48
#define HH   256
#define WWG  256
#define HW   (HH * WWG)          // 65536 = 1<<16
#define CTOT (CCS + COUT)        // 80

#define FILL_BLOCKS 2048
#define FILL_STRIDE (FILL_BLOCKS * 256)            // 524288 f4
#define TOT4        (BB * CTOT * HW / 4)           // 20,971,520 f4 (= 40 strides)

// ---------------------------------------------------------------------------
// R2-proven: blocks [0,1024): proj = emb·W + b (8 entity-rows/block, W in LDS);
// blocks [1024,1056): winner atomicMax (one entity/thread, 32 parallel blocks).
// winner[] pre-set to -1 by async memset (0xFF).
// ---------------------------------------------------------------------------
__global__ __launch_bounds__(256) void k_projwin(
        const float* __restrict__ emb, const float* __restrict__ Wm,
        const float* __restrict__ bias, const int* __restrict__ loc,
        float* __restrict__ proj, int* __restrict__ winner) {
    __shared__ float Wl[DIN * COUT];
    int tid = threadIdx.x;
    if (blockIdx.x < 1024) {
        for (int i = tid; i < DIN * COUT; i += 256) Wl[i] = Wm[i];
        __syncthreads();
        int c = tid & 31;
        int r = tid >> 5;                        // 0..7
        int row = blockIdx.x * 8 + r;            // flat entity index, 0..8191
        const float* e = emb + (size_t)row * DIN;
        float acc = bias[c];
        #pragma unroll 8
        for (int d = 0; d < DIN; ++d)
            acc += e[d] * Wl[d * COUT + c];      // e[d] uniform broadcast; conflict-free
        proj[(size_t)row * COUT + c] = acc;
    } else {
        int i = (blockIdx.x - 1024) * 256 + tid; // flat entity index
        int b = i >> 9;
        int h = loc[2 * i + 0];
        int w = loc[2 * i + 1];
        atomicMax(&winner[b * HW + h * WWG + w], i);  // max flat == last-write-wins
    }
}

// ---------------------------------------------------------------------------
// Fill, grid-stride (rocclr-fill style): 2048 persistent blocks; at each loop
// step the machine touches one contiguous 8 MB window (preserves instantaneous
// inter-wave contiguity — the property the chunked variants destroyed).
// 2-way unroll: both independent loads issue before either store.
// ch is wave-uniform (16384-f4 channel spans), so branches don't diverge.
// ---------------------------------------------------------------------------
__global__ __launch_bounds__(256) void k_fill(const float* __restrict__ sp,
                                              float* __restrict__ out) {
    size_t idx = (size_t)blockIdx.x * 256 + threadIdx.x;
    #pragma unroll 1
    for (int it = 0; it < 20; ++it, idx += 2 * (size_t)FILL_STRIDE) {
        size_t i0 = idx;
        size_t i1 = idx + FILL_STRIDE;
        int t0 = (int)(i0 >> 14);                // b*80 + ch
        int t1 = (int)(i1 >> 14);
        int b0 = t0 / CTOT, ch0 = t0 - b0 * CTOT;
        int b1 = t1 / CTOT, ch1 = t1 - b1 * CTOT;
        f4 v0 = (f4)(0.0f), v1 = (f4)(0.0f);
        if (ch0 < CCS)
            v0 = __builtin_nontemporal_load(
                (const f4*)sp + (((size_t)(b0 * CCS + ch0) << 14) + (i0 & 16383)));
        if (ch1 < CCS)
            v1 = __builtin_nontemporal_load(
                (const f4*)sp + (((size_t)(b1 * CCS + ch1) << 14) + (i1 & 16383)));
        __builtin_nontemporal_store(v0, (f4*)out + i0);
        __builtin_nontemporal_store(v1, (f4*)out + i1);
    }
}

// ---------------------------------------------------------------------------
// Winning entity writes its 32-channel proj vector to out[b, 48+c, h, w].
// ---------------------------------------------------------------------------
__global__ __launch_bounds__(256) void k_scatter(
        const float* __restrict__ proj, const int* __restrict__ loc,
        const int* __restrict__ winner, float* __restrict__ out) {
    int t = blockIdx.x * 256 + threadIdx.x;
    int c = t & 31;
    int i = t >> 5;                              // flat entity index
    int b = i >> 9;
    int h = loc[2 * i + 0];
    int w = loc[2 * i + 1];
    int cell = b * HW + h * WWG + w;
    if (winner[cell] != i) return;               // last-write-wins (max flat index)
    out[((size_t)(b * CTOT + CCS + c) << 16) + (size_t)h * WWG + w] =
        proj[(size_t)i * COUT + c];
}

extern "C" void kernel_launch(void* const* d_in, const int* in_sizes, int n_in,
                              void* d_out, int out_size, void* d_ws, size_t ws_size,
                              hipStream_t stream) {
    const float* sp   = (const float*)d_in[0];   // [16,48,256,256]
    const float* emb  = (const float*)d_in[1];   // [16,512,256]
    const float* Wm   = (const float*)d_in[2];   // [256,32]
    const float* bias = (const float*)d_in[3];   // [32]
    const int*   loc  = (const int*)d_in[4];     // [16,512,2]
    float* out = (float*)d_out;                  // [16,80,256,256]

    float* proj   = (float*)d_ws;                                     // 1 MB
    int*   winner = (int*)((char*)d_ws + (size_t)BB * NN * COUT * 4); // 4 MB

    hipMemsetAsync(winner, 0xFF, (size_t)BB * HW * sizeof(int), stream);

    hipLaunchKernelGGL(k_projwin, dim3(1024 + BB * NN / 256), dim3(256), 0, stream,
                       emb, Wm, bias, loc, proj, winner);

    hipLaunchKernelGGL(k_fill, dim3(FILL_BLOCKS), dim3(256), 0, stream,
                       sp, out);

    hipLaunchKernelGGL(k_scatter, dim3(BB * NN * COUT / 256), dim3(256), 0, stream,
                       proj, loc, winner, out);
}